// Round 3
// baseline (238.036 us; speedup 1.0000x reference)
//
#include <hip/hip_runtime.h>
#include <math.h>

#define NA 400000
#define NM 4
#define NP 512
#define ND 32
#define SQF 1.6986437f              /* sqrt(2*log2(e)) folded into BOTH operand scalings */
#define TPB 512
#define APW 64                      /* atoms per wave */
#define APB 512                     /* atoms per block (8 waves) */
#define BPM ((NA + APB - 1) / APB)  /* 782 worst-case chunks per model */
#define TPH 16                      /* p-tiles per half (16 x 16 rows = 256 points) */
#define ACUT 60.0f                  /* exact per-pair skip: drop terms < 2^-60 */

typedef __attribute__((ext_vector_type(8))) __bf16 bf16x8;
typedef __attribute__((ext_vector_type(8))) unsigned short us8;
typedef __attribute__((ext_vector_type(4))) float f32x4;

// ---- workspace layout (bytes) ----
#define WS_ZFRAG 0                  /* ushort [NM][32][2][512] = 262144 */
#define WS_AZ    262144             /* float2 [NM*512] = 16384  (alpha, -0.5*||zhat||^2) */
#define WS_ISL   278528             /* float  [NM*32]  = 512    (exp(-ls/2)*SQF)         */
#define WS_CNT   279040             /* int[4] */
#define WS_CUR   279056             /* int[4] */
#define WS_BKT   279104             /* int[NA] = 1.6 MB */

static __device__ __forceinline__ unsigned short rne_bf16(float f) {
    unsigned u = __builtin_bit_cast(unsigned, f);
    return (unsigned short)((u + 0x7fffu + ((u >> 16) & 1u)) >> 16);
}

// ---------------- fused prep (blocks 0..3) + histogram (blocks 4..) ----------------
__global__ void prep_hist_kernel(const float* __restrict__ Z,
                                 const float* __restrict__ alpha,
                                 const float* __restrict__ lls,
                                 const int* __restrict__ el,
                                 unsigned short* __restrict__ zfrag,
                                 float2* __restrict__ az,
                                 float* __restrict__ isl2,
                                 int* __restrict__ cnt)
{
    __shared__ float isl_s[ND];
    int tid = threadIdx.x;
    if (blockIdx.x < NM) {
        int m = blockIdx.x;
        if (tid < ND) {
            float v = expf(-0.5f * lls[m * ND + tid]) * SQF;
            isl_s[tid] = v;
            isl2[m * ND + tid] = v;
        }
        __syncthreads();
        for (int p = tid; p < NP; p += blockDim.x) {
            const float* zp = Z + (size_t)(m * NP + p) * ND;
            int t = p >> 4, pl = p & 15;
            size_t fb = ((size_t)(m * 32 + t) * 2) * 512;
            float z2 = 0.f;
#pragma unroll
            for (int d = 0; d < ND; ++d) {
                float zs = zp[d] * isl_s[d];
                unsigned u  = __builtin_bit_cast(unsigned, zs);
                unsigned hu = u & 0xffff0000u;
                float hif   = __builtin_bit_cast(float, hu);
                unsigned short lo = rne_bf16(zs - hif);
                float zr = hif + __builtin_bit_cast(float, (unsigned)lo << 16);
                z2 = fmaf(zr, zr, z2);
                int lane = pl + 16 * (d >> 3), j = d & 7;
                zfrag[fb +       lane * 8 + j] = (unsigned short)(hu >> 16);
                zfrag[fb + 512 + lane * 8 + j] = lo;
            }
            az[m * NP + p] = make_float2(alpha[m * NP + p], -0.5f * z2);
        }
    } else {
        int lane = tid & 63;
        int start = (blockIdx.x - NM) * blockDim.x + tid;
        int stride = (gridDim.x - NM) * blockDim.x;
        int c0 = 0, c1 = 0, c2 = 0, c3 = 0;
        for (int i = start; i < NA; i += stride) {
            int e = el[i];
            c0 += (e == 0); c1 += (e == 1); c2 += (e == 2); c3 += (e == 3);
        }
#pragma unroll
        for (int s = 1; s < 64; s <<= 1) {
            c0 += __shfl_xor(c0, s); c1 += __shfl_xor(c1, s);
            c2 += __shfl_xor(c2, s); c3 += __shfl_xor(c3, s);
        }
        if (lane == 0) {
            atomicAdd(&cnt[0], c0); atomicAdd(&cnt[1], c1);
            atomicAdd(&cnt[2], c2); atomicAdd(&cnt[3], c3);
        }
    }
}

// ---------------- scatter (ballot-ranked, two-level bases) ----------------
__global__ void scatter_kernel(const int* __restrict__ el,
                               const int* __restrict__ cnt,
                               int* __restrict__ cur,
                               int* __restrict__ bucket)
{
    __shared__ int lcnt[NM];
    __shared__ int lbase[NM];
    __shared__ int wbase_s[16][NM];
    int tid = threadIdx.x, lane = tid & 63, wv = tid >> 6;
    if (tid < NM) lcnt[tid] = 0;
    __syncthreads();
    int i = blockIdx.x * blockDim.x + tid;
    bool act = (i < NA);
    int e = act ? el[i] : -1;
    unsigned long long lt = (1ULL << lane) - 1ULL;
    int myrank = 0;
    int wcnt[NM];
#pragma unroll
    for (int mm = 0; mm < NM; ++mm) {
        unsigned long long b = __ballot(e == mm);
        if (e == mm) myrank = __popcll(b & lt);
        wcnt[mm] = __popcll(b);
    }
    if (lane == 0) {
#pragma unroll
        for (int mm = 0; mm < NM; ++mm)
            wbase_s[wv][mm] = atomicAdd(&lcnt[mm], wcnt[mm]);
    }
    __syncthreads();
    if (tid < NM) {
        int c0 = cnt[0], c1 = cnt[1], c2 = cnt[2];
        int offm = (tid == 0) ? 0 : (tid == 1) ? c0 : (tid == 2) ? c0 + c1 : c0 + c1 + c2;
        lbase[tid] = offm + atomicAdd(&cur[tid], lcnt[tid]);
    }
    __syncthreads();
    if (act) bucket[lbase[e] + wbase_s[wv][e] + myrank] = i;
}

// ---------------- main compute: split-bf16 MFMA, folded C-init, exact skip ----------------
__global__ __launch_bounds__(TPB, 8)
void gpr_kernel(const float* __restrict__ x,
                const int* __restrict__ bucket,
                const unsigned short* __restrict__ zfrag_w,
                const float2* __restrict__ az_w,
                const float* __restrict__ isl2_w,
                const int* __restrict__ cnt_w,
                float* __restrict__ out)
{
    __shared__ __align__(16) unsigned short zf[TPH][2][512];  // 32 KiB
    __shared__ __align__(16) float2 az_s[256];                // 2 KiB

    int m = blockIdx.x & 3;
    int half = (blockIdx.x >> 2) & 1;
    int chunk = blockIdx.x >> 3;
    int c0 = cnt_w[0], c1 = cnt_w[1], c2 = cnt_w[2], c3 = cnt_w[3];
    int c    = (m == 0) ? c0 : (m == 1) ? c1 : (m == 2) ? c2 : c3;
    int base = (m == 0) ? 0 : (m == 1) ? c0 : (m == 2) ? c0 + c1 : c0 + c1 + c2;
    if (chunk * APB >= c) return;               // uniform, before any barrier

    int tid = threadIdx.x;

    // stage: this (model, half)'s Z fragments (32 KiB linear) + az (2 KiB)
    {
        const int4* zg = (const int4*)(zfrag_w + (size_t)m * 32768 + (size_t)half * 16384);
        int4* zs = (int4*)&zf[0][0][0];
#pragma unroll
        for (int i = 0; i < 4; ++i) zs[tid + i * TPB] = zg[tid + i * TPB];
        if (tid < 128)
            ((float4*)az_s)[tid] = ((const float4*)(az_w + m * NP + half * 256))[tid];
    }
    __syncthreads();

    int wv = tid >> 6, lane = tid & 63;
    int lg = lane >> 4, ll = lane & 15;
    int wbase = chunk * APB + wv * APW;
    if (wbase >= c) return;                     // no barriers after this point

    int k0 = lg * 8;
    const float4* wp = (const float4*)(isl2_w + m * ND + k0);
    float4 w0 = wp[0], w1 = wp[1];

    us8 Bh[4], Bl[4];
    float x2l[4], acc[4];
#pragma unroll
    for (int nt = 0; nt < 4; ++nt) {
        int j = wbase + nt * 16 + ll;
        int jj = (j < c) ? j : (c - 1);
        int n = bucket[base + jj];
        const float4* xp = (const float4*)(x + (size_t)n * ND + k0);
        float4 a = xp[0], b = xp[1];
        float xs[8] = {a.x * w0.x, a.y * w0.y, a.z * w0.z, a.w * w0.w,
                       b.x * w1.x, b.y * w1.y, b.z * w1.z, b.w * w1.w};
        float s2 = 0.f;
#pragma unroll
        for (int i = 0; i < 8; ++i) {
            unsigned u  = __builtin_bit_cast(unsigned, xs[i]);
            unsigned hu = u & 0xffff0000u;
            float hif   = __builtin_bit_cast(float, hu);
            float lof   = xs[i] - hif;          // exact residual
            Bh[nt][i] = (unsigned short)(hu >> 16);
            Bl[nt][i] = (unsigned short)(__builtin_bit_cast(unsigned, lof) >> 16); // trunc
            s2 = fmaf(xs[i], xs[i], s2);        // fp32 norm (diff vs split ~2^-18, negligible)
        }
        s2 += __shfl_xor(s2, 16);
        s2 += __shfl_xor(s2, 32);
        x2l[nt] = 0.5f * s2;
        acc[nt] = 0.f;
    }

#pragma unroll 2
    for (int t = 0; t < TPH; ++t) {
        bf16x8 Ah = *(const bf16x8*)&zf[t][0][lane * 8];
        bf16x8 Al = *(const bf16x8*)&zf[t][1][lane * 8];
        float4 az01 = *(const float4*)&az_s[t * 16 + 4 * lg];       // (a0,-y0,a1,-y1)
        float4 az23 = *(const float4*)&az_s[t * 16 + 4 * lg + 2];   // (a2,-y2,a3,-y3)
#pragma unroll
        for (int nt = 0; nt < 4; ++nt) {
            bf16x8 bh = __builtin_bit_cast(bf16x8, Bh[nt]);
            bf16x8 bl = __builtin_bit_cast(bf16x8, Bl[nt]);
            float xl = x2l[nt];
            f32x4 d = {az01.y - xl, az01.w - xl, az23.y - xl, az23.w - xl};
            d = __builtin_amdgcn_mfma_f32_16x16x32_bf16(Al, bh, d, 0, 0, 0);
            d = __builtin_amdgcn_mfma_f32_16x16x32_bf16(Ah, bl, d, 0, 0, 0);
            d = __builtin_amdgcn_mfma_f32_16x16x32_bf16(Ah, bh, d, 0, 0, 0);
            float mx = fmaxf(fmaxf(d[0], d[1]), fmaxf(d[2], d[3]));
            if (__any(mx >= -ACUT)) {           // exact per-pair bound, ~75% skip
                acc[nt] = fmaf(az01.x, __builtin_amdgcn_exp2f(d[0]), acc[nt]);
                acc[nt] = fmaf(az01.z, __builtin_amdgcn_exp2f(d[1]), acc[nt]);
                acc[nt] = fmaf(az23.x, __builtin_amdgcn_exp2f(d[2]), acc[nt]);
                acc[nt] = fmaf(az23.z, __builtin_amdgcn_exp2f(d[3]), acc[nt]);
            }
        }
    }

#pragma unroll
    for (int nt = 0; nt < 4; ++nt) {
        float v = acc[nt];
        v += __shfl_xor(v, 16);
        v += __shfl_xor(v, 32);
        if (lane < 16) {
            int j = wbase + nt * 16 + lane;
            if (j < c) atomicAdd(&out[bucket[base + j]], v);  // 2 addends: order-invariant
        }
    }
}

// ---------------- launch ----------------
extern "C" void kernel_launch(void* const* d_in, const int* in_sizes, int n_in,
                              void* d_out, int out_size, void* d_ws, size_t ws_size,
                              hipStream_t stream)
{
    const int*   element    = (const int*)d_in[0];
    const float* x          = (const float*)d_in[1];
    const float* inducing_x = (const float*)d_in[2];
    const float* alpha      = (const float*)d_in[3];
    const float* log_ls     = (const float*)d_in[4];
    float* out = (float*)d_out;

    char* ws = (char*)d_ws;
    unsigned short* zfrag = (unsigned short*)(ws + WS_ZFRAG);
    float2* az   = (float2*)(ws + WS_AZ);
    float*  isl2 = (float*)(ws + WS_ISL);
    int*    cnt  = (int*)(ws + WS_CNT);
    int*    cur  = (int*)(ws + WS_CUR);
    int*    bkt  = (int*)(ws + WS_BKT);

    (void)in_sizes; (void)n_in; (void)out_size; (void)ws_size;

    hipMemsetAsync(cnt, 0, 8 * sizeof(int), stream);          // cnt[4] + cur[4]
    hipMemsetAsync(out, 0, NA * sizeof(float), stream);       // atomic accumulation target

    prep_hist_kernel<<<NM + 256, 256, 0, stream>>>(inducing_x, alpha, log_ls, element,
                                                   zfrag, az, isl2, cnt);
    scatter_kernel<<<(NA + 1023) / 1024, 1024, 0, stream>>>(element, cnt, cur, bkt);
    gpr_kernel<<<NM * 2 * BPM, TPB, 0, stream>>>(x, bkt, zfrag, az, isl2, cnt, out);
}

// Round 4
// 113.289 us; speedup vs baseline: 2.1011x; 2.1011x over previous
//
#include <hip/hip_runtime.h>
#include <math.h>

#define NA 400000
#define NM 4
#define NP 512
#define ND 32
#define SQF 1.6986437f              /* sqrt(2*log2(e)) folded into BOTH operand scalings */
#define TPB 512
#define APW 64                      /* atoms per wave */
#define APB 512                     /* atoms per block-iteration (8 waves) */
#define NBLK 512                    /* persistent grid: 128 blocks per model */
#define CSTRIDE (NBLK / NM)         /* 128 chunk stride */
#define ACUT 60.0f                  /* skip exp when whole 16x64 strip < 2^-60 */

typedef __attribute__((ext_vector_type(8))) __bf16 bf16x8;
typedef __attribute__((ext_vector_type(8))) unsigned short us8;
typedef __attribute__((ext_vector_type(4))) float f32x4;

// ---- workspace layout (bytes) ----
#define WS_ZFRAG 0                  /* ushort [NM][32][2][512] = 262144  (MFMA A-frag order) */
#define WS_AZ    262144             /* float2 [NM*512] = 16384  (alpha, -0.5*||zhat||^2) */
#define WS_ISL   278528             /* float  [NM*32]  = 512    (exp(-ls/2)*SQF) */
#define WS_CNT   279040             /* int[4] */
#define WS_CUR   279056             /* int[4] */
#define WS_BKT   279104             /* int[NA] = 1.6 MB */

static __device__ __forceinline__ unsigned short rne_bf16(float f) {
    unsigned u = __builtin_bit_cast(unsigned, f);
    return (unsigned short)((u + 0x7fffu + ((u >> 16) & 1u)) >> 16);
}

// ---------------- fused prep (blocks 0..3) + histogram (blocks 4..) ----------------
__global__ void prep_hist_kernel(const float* __restrict__ Z,
                                 const float* __restrict__ alpha,
                                 const float* __restrict__ lls,
                                 const int* __restrict__ el,
                                 unsigned short* __restrict__ zfrag,
                                 float2* __restrict__ az,
                                 float* __restrict__ isl2,
                                 int* __restrict__ cnt)
{
    __shared__ float isl_s[ND];
    int tid = threadIdx.x;
    if (blockIdx.x < NM) {
        int m = blockIdx.x;
        if (tid < ND) {
            float v = expf(-0.5f * lls[m * ND + tid]) * SQF;
            isl_s[tid] = v;
            isl2[m * ND + tid] = v;
        }
        __syncthreads();
        for (int p = tid; p < NP; p += blockDim.x) {
            const float* zp = Z + (size_t)(m * NP + p) * ND;
            int t = p >> 4, pl = p & 15;
            size_t fb = ((size_t)(m * 32 + t) * 2) * 512;
            float z2 = 0.f;
#pragma unroll
            for (int d = 0; d < ND; ++d) {
                float zs = zp[d] * isl_s[d];
                unsigned u  = __builtin_bit_cast(unsigned, zs);
                unsigned hu = u & 0xffff0000u;
                float hif   = __builtin_bit_cast(float, hu);
                unsigned short lo = rne_bf16(zs - hif);
                float zr = hif + __builtin_bit_cast(float, (unsigned)lo << 16);
                z2 = fmaf(zr, zr, z2);
                int lane = pl + 16 * (d >> 3), j = d & 7;
                zfrag[fb +       lane * 8 + j] = (unsigned short)(hu >> 16);
                zfrag[fb + 512 + lane * 8 + j] = lo;
            }
            az[m * NP + p] = make_float2(alpha[m * NP + p], -0.5f * z2);
        }
    } else {
        int lane = tid & 63;
        int start = (blockIdx.x - NM) * blockDim.x + tid;
        int stride = (gridDim.x - NM) * blockDim.x;
        int c0 = 0, c1 = 0, c2 = 0, c3 = 0;
        for (int i = start; i < NA; i += stride) {
            int e = el[i];
            c0 += (e == 0); c1 += (e == 1); c2 += (e == 2); c3 += (e == 3);
        }
#pragma unroll
        for (int s = 1; s < 64; s <<= 1) {
            c0 += __shfl_xor(c0, s); c1 += __shfl_xor(c1, s);
            c2 += __shfl_xor(c2, s); c3 += __shfl_xor(c3, s);
        }
        if (lane == 0) {
            atomicAdd(&cnt[0], c0); atomicAdd(&cnt[1], c1);
            atomicAdd(&cnt[2], c2); atomicAdd(&cnt[3], c3);
        }
    }
}

// ---------------- scatter (ballot-ranked, two-level bases) ----------------
__global__ void scatter_kernel(const int* __restrict__ el,
                               const int* __restrict__ cnt,
                               int* __restrict__ cur,
                               int* __restrict__ bucket)
{
    __shared__ int lcnt[NM];
    __shared__ int lbase[NM];
    __shared__ int wbase_s[16][NM];
    int tid = threadIdx.x, lane = tid & 63, wv = tid >> 6;
    if (tid < NM) lcnt[tid] = 0;
    __syncthreads();
    int i = blockIdx.x * blockDim.x + tid;
    bool act = (i < NA);
    int e = act ? el[i] : -1;
    unsigned long long lt = (1ULL << lane) - 1ULL;
    int myrank = 0;
    int wcnt[NM];
#pragma unroll
    for (int mm = 0; mm < NM; ++mm) {
        unsigned long long b = __ballot(e == mm);
        if (e == mm) myrank = __popcll(b & lt);
        wcnt[mm] = __popcll(b);
    }
    if (lane == 0) {
#pragma unroll
        for (int mm = 0; mm < NM; ++mm)
            wbase_s[wv][mm] = atomicAdd(&lcnt[mm], wcnt[mm]);
    }
    __syncthreads();
    if (tid < NM) {
        int c0 = cnt[0], c1 = cnt[1], c2 = cnt[2];
        int offm = (tid == 0) ? 0 : (tid == 1) ? c0 : (tid == 2) ? c0 + c1 : c0 + c1 + c2;
        lbase[tid] = offm + atomicAdd(&cur[tid], lcnt[tid]);
    }
    __syncthreads();
    if (act) bucket[lbase[e] + wbase_s[wv][e] + myrank] = i;
}

// ---------------- main compute: split-bf16 MFMA, folded C-init, exact skip ----------------
__global__ __launch_bounds__(TPB, 4)
void gpr_kernel(const float* __restrict__ x,
                const int* __restrict__ bucket,
                const unsigned short* __restrict__ zfrag_w,
                const float2* __restrict__ az_w,
                const float* __restrict__ isl2_w,
                const int* __restrict__ cnt_w,
                float* __restrict__ out)
{
    __shared__ __align__(16) unsigned short zf[32][2][512];   // 64 KiB
    __shared__ __align__(16) float2 az_s[NP];                 // 4 KiB

    int m = blockIdx.x & 3;
    int chunk0 = blockIdx.x >> 2;
    int c0 = cnt_w[0], c1 = cnt_w[1], c2 = cnt_w[2], c3 = cnt_w[3];
    int c    = (m == 0) ? c0 : (m == 1) ? c1 : (m == 2) ? c2 : c3;
    int base = (m == 0) ? 0 : (m == 1) ? c0 : (m == 2) ? c0 + c1 : c0 + c1 + c2;
    if (chunk0 * APB >= c) return;               // uniform, before any barrier

    int tid = threadIdx.x;

    // stage once: this model's Z fragments (64 KiB linear) + az (4 KiB)
    {
        const int4* zg = (const int4*)(zfrag_w + (size_t)m * 32768);
        int4* zs = (int4*)&zf[0][0][0];
#pragma unroll
        for (int i = 0; i < 8; ++i) zs[tid + i * TPB] = zg[tid + i * TPB];
        if (tid < 256)
            ((float4*)az_s)[tid] = ((const float4*)(az_w + m * NP))[tid];
    }
    __syncthreads();                              // last barrier in the kernel

    int wv = tid >> 6, lane = tid & 63;
    int lg = lane >> 4, ll = lane & 15;
    int k0 = lg * 8;
    const float4* wp = (const float4*)(isl2_w + m * ND + k0);
    float4 w0 = wp[0], w1 = wp[1];

    for (int chunk = chunk0; chunk * APB < c; chunk += CSTRIDE) {
        int wbase = chunk * APB + wv * APW;
        if (wbase >= c) continue;

        us8 Bh[4], Bl[4];
        float x2l[4], acc[4];
#pragma unroll
        for (int nt = 0; nt < 4; ++nt) {
            int j = wbase + nt * 16 + ll;
            int jj = (j < c) ? j : (c - 1);
            int n = bucket[base + jj];
            const float4* xp = (const float4*)(x + (size_t)n * ND + k0);
            float4 a = xp[0], b = xp[1];
            float xs[8] = {a.x * w0.x, a.y * w0.y, a.z * w0.z, a.w * w0.w,
                           b.x * w1.x, b.y * w1.y, b.z * w1.z, b.w * w1.w};
            float s2 = 0.f;
#pragma unroll
            for (int i = 0; i < 8; ++i) {
                unsigned u  = __builtin_bit_cast(unsigned, xs[i]);
                unsigned hu = u & 0xffff0000u;
                float hif   = __builtin_bit_cast(float, hu);
                float lof   = xs[i] - hif;        // exact residual
                Bh[nt][i] = (unsigned short)(hu >> 16);
                Bl[nt][i] = (unsigned short)(__builtin_bit_cast(unsigned, lof) >> 16);
                s2 = fmaf(xs[i], xs[i], s2);
            }
            s2 += __shfl_xor(s2, 16);
            s2 += __shfl_xor(s2, 32);
            x2l[nt] = 0.5f * s2;
            acc[nt] = 0.f;
        }

#pragma unroll 2
        for (int t = 0; t < 32; ++t) {
            bf16x8 Ah = *(const bf16x8*)&zf[t][0][lane * 8];
            bf16x8 Al = *(const bf16x8*)&zf[t][1][lane * 8];
            float4 az01 = *(const float4*)&az_s[t * 16 + 4 * lg];       // (a0,-y0,a1,-y1)
            float4 az23 = *(const float4*)&az_s[t * 16 + 4 * lg + 2];   // (a2,-y2,a3,-y3)
#pragma unroll
            for (int nt = 0; nt < 4; ++nt) {
                bf16x8 bh = __builtin_bit_cast(bf16x8, Bh[nt]);
                bf16x8 bl = __builtin_bit_cast(bf16x8, Bl[nt]);
                float xl = x2l[nt];
                f32x4 d = {az01.y - xl, az01.w - xl, az23.y - xl, az23.w - xl};
                d = __builtin_amdgcn_mfma_f32_16x16x32_bf16(Al, bh, d, 0, 0, 0);
                d = __builtin_amdgcn_mfma_f32_16x16x32_bf16(Ah, bl, d, 0, 0, 0);
                d = __builtin_amdgcn_mfma_f32_16x16x32_bf16(Ah, bh, d, 0, 0, 0);
                float mx = fmaxf(fmaxf(d[0], d[1]), fmaxf(d[2], d[3]));
                if (__any(mx >= -ACUT)) {          // exact per-pair bound, ~74% skip
                    acc[nt] = fmaf(az01.x, __builtin_amdgcn_exp2f(d[0]), acc[nt]);
                    acc[nt] = fmaf(az01.z, __builtin_amdgcn_exp2f(d[1]), acc[nt]);
                    acc[nt] = fmaf(az23.x, __builtin_amdgcn_exp2f(d[2]), acc[nt]);
                    acc[nt] = fmaf(az23.z, __builtin_amdgcn_exp2f(d[3]), acc[nt]);
                }
            }
        }

#pragma unroll
        for (int nt = 0; nt < 4; ++nt) {
            float v = acc[nt];
            v += __shfl_xor(v, 16);
            v += __shfl_xor(v, 32);
            if (lane < 16) {
                int j = wbase + nt * 16 + lane;
                if (j < c) out[bucket[base + j]] = v;
            }
        }
    }
}

// ---------------- launch ----------------
extern "C" void kernel_launch(void* const* d_in, const int* in_sizes, int n_in,
                              void* d_out, int out_size, void* d_ws, size_t ws_size,
                              hipStream_t stream)
{
    const int*   element    = (const int*)d_in[0];
    const float* x          = (const float*)d_in[1];
    const float* inducing_x = (const float*)d_in[2];
    const float* alpha      = (const float*)d_in[3];
    const float* log_ls     = (const float*)d_in[4];
    float* out = (float*)d_out;

    char* ws = (char*)d_ws;
    unsigned short* zfrag = (unsigned short*)(ws + WS_ZFRAG);
    float2* az   = (float2*)(ws + WS_AZ);
    float*  isl2 = (float*)(ws + WS_ISL);
    int*    cnt  = (int*)(ws + WS_CNT);
    int*    cur  = (int*)(ws + WS_CUR);
    int*    bkt  = (int*)(ws + WS_BKT);

    (void)in_sizes; (void)n_in; (void)out_size; (void)ws_size;

    hipMemsetAsync(cnt, 0, 8 * sizeof(int), stream);          // cnt[4] + cur[4]

    prep_hist_kernel<<<NM + 256, 256, 0, stream>>>(inducing_x, alpha, log_ls, element,
                                                   zfrag, az, isl2, cnt);
    scatter_kernel<<<(NA + 1023) / 1024, 1024, 0, stream>>>(element, cnt, cur, bkt);
    gpr_kernel<<<NBLK, TPB, 0, stream>>>(x, bkt, zfrag, az, isl2, cnt, out);
}